// Round 6
// baseline (188.003 us; speedup 1.0000x reference)
//
#include <hip/hip_runtime.h>
#include <math.h>

#define NN 50000
#define NE 800000
#define BINW 512
#define NB ((NN + BINW - 1) / BINW)   // 98 buckets
#define CAP 12288                     // per-bucket capacity (mean 8192, sd ~90)
#define CHUNK 4096

typedef __attribute__((ext_vector_type(8))) short short8;
typedef __attribute__((ext_vector_type(4))) float f32x4;
typedef unsigned int uint32;

__device__ inline unsigned short f2bf(float f) {
    unsigned u = __builtin_bit_cast(unsigned, f);
    u += 0x7FFF + ((u >> 16) & 1);   // RNE
    return (unsigned short)(u >> 16);
}
__device__ inline float bf_lo(uint32 v) { return __builtin_bit_cast(float, v << 16); }
__device__ inline float bf_hi(uint32 v) { return __builtin_bit_cast(float, v & 0xFFFF0000u); }

__device__ inline int edge_at(const void* edges, int is64, int i) {
    return is64 ? (int)((const long long*)edges)[i] : ((const int*)edges)[i];
}

// ---------------------------------------------------------------------------
// init: zero bucket counters; detect edge dtype (int64 vs int32) into flag
// ---------------------------------------------------------------------------
__global__ void k_init(int* flag, int* bcnt, const void* edges) {
    int i = blockIdx.x * 256 + threadIdx.x;
    if (i < NB) bcnt[i] = 0;
    if (blockIdx.x == 0 && threadIdx.x < 64) {
        const long long* q = (const long long*)edges;
        long long v = q[threadIdx.x];
        int ok = (v >= 0 && v < NN) ? 1 : 0;
        unsigned long long m = __ballot(ok);
        if (threadIdx.x == 0) *flag = (m == ~0ull) ? 1 : 0;
    }
}

// ---------------------------------------------------------------------------
// k_bin: coarse counting-sort of edges into NB buckets by dst>>9.
// ---------------------------------------------------------------------------
__global__ __launch_bounds__(256) void k_bin(const void* __restrict__ edges,
                                             const int* __restrict__ flag,
                                             uint32* __restrict__ gbuf,
                                             int* __restrict__ bcnt) {
    __shared__ int hist[NB], excl[NB + 1], cur[NB], gpos[NB];
    __shared__ uint32 sorted[CHUNK];
    int t = threadIdx.x;
    int base = blockIdx.x * CHUNK;
    int n = NE - base; if (n > CHUNK) n = CHUNK;
    int is64 = *flag;
    for (int i = t; i < NB; i += 256) hist[i] = 0;
    __syncthreads();
    for (int i = t; i < n; i += 256) {
        int dst = edge_at(edges, is64, NE + base + i);
        atomicAdd(&hist[dst >> 9], 1);
    }
    __syncthreads();
    if (t == 0) {
        int s = 0;
        for (int b = 0; b < NB; ++b) { excl[b] = s; s += hist[b]; }
        excl[NB] = s;
    }
    __syncthreads();
    if (t < NB) {
        gpos[t] = atomicAdd(&bcnt[t], hist[t]);
        cur[t] = excl[t];
    }
    __syncthreads();
    for (int i = t; i < n; i += 256) {
        int src = edge_at(edges, is64, base + i);
        int dst = edge_at(edges, is64, NE + base + i);
        int b = dst >> 9;
        int lp = atomicAdd(&cur[b], 1);
        sorted[lp] = ((uint32)(dst & (BINW - 1)) << 16) | (uint32)src;
    }
    __syncthreads();
    for (int i = t; i < n; i += 256) {
        int lo = 0, hi = NB - 1;
        while (lo < hi) { int mid = (lo + hi + 1) >> 1; if (excl[mid] <= i) lo = mid; else hi = mid - 1; }
        int gp = gpos[lo] + (i - excl[lo]);
        if (gp < CAP) gbuf[(size_t)lo * CAP + gp] = sorted[i];
    }
}

// tiny scan of bucket counts -> bucket bases; offs[NN] = NE
__global__ void k_bbase(const int* __restrict__ bcnt, int* __restrict__ bbase,
                        int* __restrict__ offs) {
    if (threadIdx.x == 0) {
        int s = 0;
        for (int b = 0; b < NB; ++b) { bbase[b] = s; s += bcnt[b]; }
        offs[NN] = s;
    }
}

// ---------------------------------------------------------------------------
// k_sort: one block per bucket -> offs[] + dst-sorted src list (uint16)
// ---------------------------------------------------------------------------
__global__ __launch_bounds__(256) void k_sort(const uint32* __restrict__ gbuf,
                                              const int* __restrict__ bcnt,
                                              const int* __restrict__ bbase,
                                              int* __restrict__ offs,
                                              unsigned short* __restrict__ ssrc) {
    __shared__ int hist[BINW], cur[BINW], wsum[4];
    __shared__ int sorted[CAP];
    int b = blockIdx.x, t = threadIdx.x;
    int cnt = bcnt[b]; if (cnt > CAP) cnt = CAP;
    int nbase = b * BINW;
    int ncnt = NN - nbase; if (ncnt > BINW) ncnt = BINW;
    for (int i = t; i < BINW; i += 256) hist[i] = 0;
    __syncthreads();
    for (int i = t; i < cnt; i += 256)
        atomicAdd(&hist[gbuf[(size_t)b * CAP + i] >> 16], 1);
    __syncthreads();
    int lane = t & 63, w = t >> 6;
    int d0 = hist[2 * t], d1 = hist[2 * t + 1];
    int v = d0 + d1;
    #pragma unroll
    for (int d = 1; d < 64; d <<= 1) { int x = __shfl_up(v, d); if (lane >= d) v += x; }
    if (lane == 63) wsum[w] = v;
    __syncthreads();
    if (t == 0) { int s = 0; for (int i = 0; i < 4; ++i) { int x = wsum[i]; wsum[i] = s; s += x; } }
    __syncthreads();
    int e0 = wsum[w] + (v - d0 - d1);
    int e1 = e0 + d0;
    if (2 * t < ncnt)     offs[nbase + 2 * t]     = bbase[b] + e0;
    if (2 * t + 1 < ncnt) offs[nbase + 2 * t + 1] = bbase[b] + e1;
    cur[2 * t] = e0; cur[2 * t + 1] = e1;
    __syncthreads();
    for (int i = t; i < cnt; i += 256) {
        uint32 p = gbuf[(size_t)b * CAP + i];
        int lp = atomicAdd(&cur[p >> 16], 1);
        sorted[lp] = (int)(p & 0xFFFFu);
    }
    __syncthreads();
    for (int i = t; i < cnt; i += 256)
        ssrc[bbase[b] + i] = (unsigned short)sorted[i];
}

// ---------------------------------------------------------------------------
// x fp32 [NN,128] -> bf16 into A1 cols 128:256 (A1 is [NN,256] bf16)
// ---------------------------------------------------------------------------
__global__ void k_cvt_x(const float* __restrict__ x, unsigned short* __restrict__ A1) {
    int t = blockIdx.x * 256 + threadIdx.x;
    if (t >= NN * 32) return;
    int node = t >> 5, q = t & 31;
    float4 v = *(const float4*)(x + (size_t)node * 128 + q * 4);
    uint32 p0 = f2bf(v.x) | ((uint32)f2bf(v.y) << 16);
    uint32 p1 = f2bf(v.z) | ((uint32)f2bf(v.w) << 16);
    *(uint2*)(A1 + (size_t)node * 256 + 128 + q * 4) = make_uint2(p0, p1);
}

// pack both weight matrices, n-major transposed bf16 [256][256]
__global__ void k_cvt_w(const float* __restrict__ W1l, const float* __restrict__ W1r,
                        const float* __restrict__ W2l, const float* __restrict__ W2r,
                        unsigned short* __restrict__ B1t, unsigned short* __restrict__ B2t) {
    int t = blockIdx.x * 256 + threadIdx.x;
    if (t >= 65536) return;
    int n = t >> 8, k = t & 255;
    float v1 = (k < 128) ? W1l[k * 256 + n] : W1r[(k - 128) * 256 + n];
    B1t[n * 256 + k] = f2bf(v1);
    float v2 = (n < 128) ? W2l[k * 128 + n] : W2r[k * 128 + (n - 128)];
    B2t[n * 256 + k] = f2bf(v2);
}

// ---------------------------------------------------------------------------
// paired burst-gather: wave splits into 2 halves of 32 lanes; each half loads
// 8B (4 channels) of one edge row -> one instruction fetches TWO edge rows.
// ---------------------------------------------------------------------------
#define ACC4(vv) { a0 += bf_lo((vv).x); a1 += bf_hi((vv).x); \
                   a2 += bf_lo((vv).y); a3 += bf_hi((vv).y); }

__device__ inline void burst_gather2(const unsigned short* __restrict__ tab, int coff,
                                     const unsigned short* __restrict__ ssrc, int s0, int s1,
                                     int lane, float& a0, float& a1, float& a2, float& a3) {
    int half = lane >> 5, cl = lane & 31;
    const unsigned short* bp = tab + coff + cl * 4;
    int e = s0;
    while (e < s1) {
        int cnt = s1 - e; if (cnt > 64) cnt = 64;
        int myidx = (lane < cnt) ? (int)ssrc[e + lane] : 0;
        int fp = cnt >> 1;   // full pairs
        int b = 0;
        for (; b + 8 <= fp; b += 8) {       // 16 edges in flight
            uint2 v[8];
            #pragma unroll
            for (int u = 0; u < 8; ++u) {
                int s = __shfl(myidx, 2 * (b + u) + half);
                v[u] = *(const uint2*)(bp + (size_t)s * 256);
            }
            #pragma unroll
            for (int u = 0; u < 8; ++u) ACC4(v[u]);
        }
        for (; b + 4 <= fp; b += 4) {
            uint2 v[4];
            #pragma unroll
            for (int u = 0; u < 4; ++u) {
                int s = __shfl(myidx, 2 * (b + u) + half);
                v[u] = *(const uint2*)(bp + (size_t)s * 256);
            }
            #pragma unroll
            for (int u = 0; u < 4; ++u) ACC4(v[u]);
        }
        for (; b < fp; ++b) {
            int s = __shfl(myidx, 2 * b + half);
            uint2 v = *(const uint2*)(bp + (size_t)s * 256);
            ACC4(v);
        }
        if (cnt & 1) {                      // odd tail: half 0 only
            int s = __shfl(myidx, cnt - 1);
            uint2 v = *(const uint2*)(bp + (size_t)s * 256);
            if (half == 0) ACC4(v);
        }
        e += cnt;
    }
}

// ---------------------------------------------------------------------------
// mean-aggregate bf16 rows (A1 cols 128:256) -> bf16 (A1 cols 0:128)
// ---------------------------------------------------------------------------
__global__ void k_agg(unsigned short* __restrict__ A1, const int* __restrict__ offs,
                      const unsigned short* __restrict__ ssrc) {
    int node = blockIdx.x * 4 + (threadIdx.x >> 6);
    int lane = threadIdx.x & 63;
    if (node >= NN) return;
    int s0 = offs[node], s1 = offs[node + 1];
    float a0 = 0.f, a1 = 0.f, a2 = 0.f, a3 = 0.f;
    burst_gather2(A1, 128, ssrc, s0, s1, lane, a0, a1, a2, a3);
    a0 += __shfl_xor(a0, 32); a1 += __shfl_xor(a1, 32);
    a2 += __shfl_xor(a2, 32); a3 += __shfl_xor(a3, 32);
    float inv = 1.0f / fmaxf((float)(s1 - s0), 1.0f);
    if (lane < 32) {
        uint32 p0 = f2bf(a0 * inv) | ((uint32)f2bf(a1 * inv) << 16);
        uint32 p1 = f2bf(a2 * inv) | ((uint32)f2bf(a3 * inv) << 16);
        *(uint2*)(A1 + (size_t)node * 256 + lane * 4) = make_uint2(p0, p1);
    }
}

// ---------------------------------------------------------------------------
// fused GEMM: per 64-row M-tile, phase1 h = relu(A1@B1+b1) -> LDS,
// phase2 Pb = h@B2 -> global. 8 waves (2x4), wave-tile 32x64.
// A staged (dbuf LDS); B frags direct from L2-hot 128KB tables.
// ---------------------------------------------------------------------------
__global__ __launch_bounds__(512)
void k_gemm_fused(const unsigned short* __restrict__ A,
                  const unsigned short* __restrict__ B1t,
                  const float* __restrict__ b1,
                  const unsigned short* __restrict__ B2t,
                  unsigned short* __restrict__ Pb) {
    constexpr int LDK = 40;
    __shared__ unsigned short Asm[2][64][LDK];
    __shared__ unsigned short Hs[64][264];
    int t = threadIdx.x;
    int lane = t & 63, w = t >> 6;
    int m0 = blockIdx.x * 64;
    int wr = (w >> 2) * 32, wc = (w & 3) * 64;
    int fr = lane & 15, fk = (lane >> 4) * 8;

    // A staging: 64 rows x 32 cols = 256 short8, threads 0..255
    int mlA = t >> 2, subA = t & 3;
    bool stager = t < 256;
    int gmA = m0 + mlA;
    bool okA = stager && (gmA < NN);
    const short8* pa = (const short8*)(A + (size_t)gmA * 256 + subA * 8);
    const short8 zero = {};
    short8 va;

    f32x4 acc[2][4] = {};
    // ---- phase 1
    va = okA ? pa[0] : zero;
    if (stager) *(short8*)&Asm[0][mlA][subA * 8] = va;
    __syncthreads();
    int cur = 0;
    #pragma unroll
    for (int ks = 0; ks < 8; ++ks) {
        if (ks < 7) va = okA ? pa[(ks + 1) * 4] : zero;
        short8 af[2], bfr[4];
        #pragma unroll
        for (int j = 0; j < 4; ++j)
            bfr[j] = *(const short8*)(B1t + (size_t)(wc + j * 16 + fr) * 256 + ks * 32 + fk);
        #pragma unroll
        for (int i = 0; i < 2; ++i)
            af[i] = *(const short8*)&Asm[cur][wr + i * 16 + fr][fk];
        #pragma unroll
        for (int i = 0; i < 2; ++i)
            #pragma unroll
            for (int j = 0; j < 4; ++j)
                acc[i][j] = __builtin_amdgcn_mfma_f32_16x16x32_bf16(af[i], bfr[j], acc[i][j], 0, 0, 0);
        if (ks < 7) {
            if (stager) *(short8*)&Asm[cur ^ 1][mlA][subA * 8] = va;
            __syncthreads();
            cur ^= 1;
        }
    }
    // h epilogue -> Hs (bias + relu)
    int r0 = (lane >> 4) * 4;
    #pragma unroll
    for (int j = 0; j < 4; ++j) {
        int col = wc + j * 16 + fr;
        float bb = b1[col];
        #pragma unroll
        for (int i = 0; i < 2; ++i)
            #pragma unroll
            for (int rr = 0; rr < 4; ++rr)
                Hs[wr + i * 16 + r0 + rr][col] = f2bf(fmaxf(acc[i][j][rr] + bb, 0.f));
    }
    __syncthreads();
    // ---- phase 2 (no barriers: Hs read-only, B2 from global)
    f32x4 acc2[2][4] = {};
    #pragma unroll
    for (int ks = 0; ks < 8; ++ks) {
        short8 af[2], bfr[4];
        #pragma unroll
        for (int j = 0; j < 4; ++j)
            bfr[j] = *(const short8*)(B2t + (size_t)(wc + j * 16 + fr) * 256 + ks * 32 + fk);
        #pragma unroll
        for (int i = 0; i < 2; ++i)
            af[i] = *(const short8*)&Hs[wr + i * 16 + fr][ks * 32 + fk];
        #pragma unroll
        for (int i = 0; i < 2; ++i)
            #pragma unroll
            for (int j = 0; j < 4; ++j)
                acc2[i][j] = __builtin_amdgcn_mfma_f32_16x16x32_bf16(af[i], bfr[j], acc2[i][j], 0, 0, 0);
    }
    // Pb epilogue
    #pragma unroll
    for (int i = 0; i < 2; ++i)
        #pragma unroll
        for (int j = 0; j < 4; ++j) {
            int gn = wc + j * 16 + fr;
            #pragma unroll
            for (int rr = 0; rr < 4; ++rr) {
                int gm = m0 + wr + i * 16 + r0 + rr;
                if (gm < NN) Pb[(size_t)gm * 256 + gn] = f2bf(acc2[i][j][rr]);
            }
        }
}

// ---------------------------------------------------------------------------
// out = log_softmax( mean_agg(p) + r + b2 ); p = P cols 0:128, r = cols 128:256
// ---------------------------------------------------------------------------
__global__ void k_final(const unsigned short* __restrict__ P, const int* __restrict__ offs,
                        const unsigned short* __restrict__ ssrc, const float* __restrict__ b2,
                        float* __restrict__ out) {
    int node = blockIdx.x * 4 + (threadIdx.x >> 6);
    int lane = threadIdx.x & 63;
    if (node >= NN) return;
    int cl = lane & 31;
    int s0 = offs[node], s1 = offs[node + 1];
    float a0 = 0.f, a1 = 0.f, a2 = 0.f, a3 = 0.f;
    burst_gather2(P, 0, ssrc, s0, s1, lane, a0, a1, a2, a3);
    a0 += __shfl_xor(a0, 32); a1 += __shfl_xor(a1, 32);
    a2 += __shfl_xor(a2, 32); a3 += __shfl_xor(a3, 32);
    float inv = 1.0f / fmaxf((float)(s1 - s0), 1.0f);
    uint2 rv = *(const uint2*)(P + (size_t)node * 256 + 128 + cl * 4);
    float4 bb = *(const float4*)(b2 + cl * 4);
    float v0 = a0 * inv + bf_lo(rv.x) + bb.x;
    float v1 = a1 * inv + bf_hi(rv.x) + bb.y;
    float v2 = a2 * inv + bf_lo(rv.y) + bb.z;
    float v3 = a3 * inv + bf_hi(rv.y) + bb.w;

    float mx = fmaxf(fmaxf(v0, v1), fmaxf(v2, v3));
    #pragma unroll
    for (int d = 1; d < 64; d <<= 1) mx = fmaxf(mx, __shfl_xor(mx, d));
    float s = __expf(v0 - mx) + __expf(v1 - mx) + __expf(v2 - mx) + __expf(v3 - mx);
    #pragma unroll
    for (int d = 1; d < 64; d <<= 1) s += __shfl_xor(s, d);
    float ls = logf(s * 0.5f);   // both halves hold all 128 ch -> sum is doubled
    if (lane < 32)
        *(float4*)(out + (size_t)node * 128 + cl * 4) =
            make_float4(v0 - mx - ls, v1 - mx - ls, v2 - mx - ls, v3 - mx - ls);
}

// ---------------------------------------------------------------------------
extern "C" void kernel_launch(void* const* d_in, const int* in_sizes, int n_in,
                              void* d_out, int out_size, void* d_ws, size_t ws_size,
                              hipStream_t stream) {
    const float* x   = (const float*)d_in[0];
    const void*  edg = d_in[1];
    const float* W1l = (const float*)d_in[2];
    const float* W1r = (const float*)d_in[3];
    const float* b1  = (const float*)d_in[4];
    const float* W2l = (const float*)d_in[5];
    const float* W2r = (const float*)d_in[6];
    const float* b2  = (const float*)d_in[7];
    float* out = (float*)d_out;

    char* ws = (char*)d_ws;
    size_t off = 0;
    auto alloc = [&](size_t bytes) {
        size_t cur = off;
        off = (off + bytes + 255) & ~(size_t)255;
        return cur;
    };
    int* flag  = (int*)(ws + alloc(4));
    int* bcnt  = (int*)(ws + alloc((size_t)NB * 4));
    int* bbase = (int*)(ws + alloc((size_t)NB * 4));
    int* offs  = (int*)(ws + alloc((size_t)(NN + 1) * 4));
    unsigned short* ssrc = (unsigned short*)(ws + alloc((size_t)NE * 2));
    uint32* gbuf = (uint32*)(ws + alloc((size_t)NB * CAP * 4));              // 4.8MB
    unsigned short* A1  = (unsigned short*)(ws + alloc((size_t)NN * 256 * 2)); // [agg|x] bf16
    unsigned short* Pb  = (unsigned short*)(ws + alloc((size_t)NN * 256 * 2)); // [p|r] bf16
    unsigned short* B1t = (unsigned short*)(ws + alloc((size_t)65536 * 2));
    unsigned short* B2t = (unsigned short*)(ws + alloc((size_t)65536 * 2));

    int nb_n = (NN + 255) / 256;
    int nb_w = (NN + 3) / 4;
    int fblocks = (NN + 63) / 64;              // 782
    int binblocks = (NE + CHUNK - 1) / CHUNK;  // 196

    k_init<<<nb_n, 256, 0, stream>>>(flag, bcnt, edg);
    k_cvt_x<<<(NN * 32 + 255) / 256, 256, 0, stream>>>(x, A1);
    k_cvt_w<<<256, 256, 0, stream>>>(W1l, W1r, W2l, W2r, B1t, B2t);
    k_bin<<<binblocks, 256, 0, stream>>>(edg, flag, gbuf, bcnt);
    k_bbase<<<1, 64, 0, stream>>>(bcnt, bbase, offs);
    k_sort<<<NB, 256, 0, stream>>>(gbuf, bcnt, bbase, offs, ssrc);
    // agg1 -> A1 cols 0:128
    k_agg<<<nb_w, 256, 0, stream>>>(A1, offs, ssrc);
    // fused: h = relu(A1@B1+b1) (LDS), Pb = h@B2
    k_gemm_fused<<<fblocks, 512, 0, stream>>>(A1, B1t, b1, B2t, Pb);
    // out = log_softmax(mean_agg(p) + r + b2)
    k_final<<<nb_w, 256, 0, stream>>>(Pb, offs, ssrc, b2, out);
}

// Round 7
// 157.225 us; speedup vs baseline: 1.1958x; 1.1958x over previous
//
#include <hip/hip_runtime.h>
#include <math.h>

#define NN 50000
#define NE 800000
#define BINW 512
#define NB ((NN + BINW - 1) / BINW)   // 98 buckets
#define CAP 12288                     // per-bucket capacity (mean 8192, sd ~90)
#define CHUNK 4096
#define EPT 16                        // edges per thread in k_bin

typedef __attribute__((ext_vector_type(8))) short short8;
typedef __attribute__((ext_vector_type(4))) float f32x4;
typedef unsigned int uint32;

__device__ inline unsigned short f2bf(float f) {
    unsigned u = __builtin_bit_cast(unsigned, f);
    u += 0x7FFF + ((u >> 16) & 1);   // RNE
    return (unsigned short)(u >> 16);
}
__device__ inline float bf_lo(uint32 v) { return __builtin_bit_cast(float, v << 16); }
__device__ inline float bf_hi(uint32 v) { return __builtin_bit_cast(float, v & 0xFFFF0000u); }

__device__ inline int edge_at(const void* edges, int is64, int i) {
    return is64 ? (int)((const long long*)edges)[i] : ((const int*)edges)[i];
}

// ---------------------------------------------------------------------------
// k_prep: one launch does cvt_x, cvt_w, and init (flag + bucket counters)
// blocks [0,6250): x fp32 -> bf16 into A1 cols 128:256
// blocks [6250,6506): weights -> n-major bf16 tables
// block 6506: zero bcnt, detect edge dtype
// ---------------------------------------------------------------------------
__global__ void k_prep(const float* __restrict__ x, unsigned short* __restrict__ A1,
                       const float* __restrict__ W1l, const float* __restrict__ W1r,
                       const float* __restrict__ W2l, const float* __restrict__ W2r,
                       unsigned short* __restrict__ B1t, unsigned short* __restrict__ B2t,
                       int* flag, int* bcnt, const void* edges) {
    int b = blockIdx.x;
    if (b < 6250) {
        int t = b * 256 + threadIdx.x;
        if (t >= NN * 32) return;
        int node = t >> 5, q = t & 31;
        float4 v = *(const float4*)(x + (size_t)node * 128 + q * 4);
        uint32 p0 = f2bf(v.x) | ((uint32)f2bf(v.y) << 16);
        uint32 p1 = f2bf(v.z) | ((uint32)f2bf(v.w) << 16);
        *(uint2*)(A1 + (size_t)node * 256 + 128 + q * 4) = make_uint2(p0, p1);
    } else if (b < 6506) {
        int t = (b - 6250) * 256 + threadIdx.x;
        int n = t >> 8, k = t & 255;
        float v1 = (k < 128) ? W1l[k * 256 + n] : W1r[(k - 128) * 256 + n];
        B1t[n * 256 + k] = f2bf(v1);
        float v2 = (n < 128) ? W2l[k * 128 + n] : W2r[k * 128 + (n - 128)];
        B2t[n * 256 + k] = f2bf(v2);
    } else {
        if (threadIdx.x < NB) bcnt[threadIdx.x] = 0;
        if (threadIdx.x < 64) {
            const long long* q = (const long long*)edges;
            long long v = q[threadIdx.x];
            int ok = (v >= 0 && v < NN) ? 1 : 0;
            unsigned long long m = __ballot(ok);
            if (threadIdx.x == 0) *flag = (m == ~0ull) ? 1 : 0;
        }
    }
}

// ---------------------------------------------------------------------------
// k_bin: coarse counting-sort of edges into NB buckets by dst>>9.
// Edges cached in registers (read once).
// ---------------------------------------------------------------------------
__global__ __launch_bounds__(256) void k_bin(const void* __restrict__ edges,
                                             const int* __restrict__ flag,
                                             uint32* __restrict__ gbuf,
                                             int* __restrict__ bcnt) {
    __shared__ int hist[NB], excl[NB + 1], cur[NB], gpos[NB];
    __shared__ uint32 sorted[CHUNK];
    int t = threadIdx.x;
    int base = blockIdx.x * CHUNK;
    int n = NE - base; if (n > CHUNK) n = CHUNK;
    int is64 = *flag;
    int sA[EPT], dA[EPT];
    #pragma unroll
    for (int q = 0; q < EPT; ++q) {
        int i = t + q * 256;
        if (i < n) {
            sA[q] = edge_at(edges, is64, base + i);
            dA[q] = edge_at(edges, is64, NE + base + i);
        } else dA[q] = -1;
    }
    for (int i = t; i < NB; i += 256) hist[i] = 0;
    __syncthreads();
    #pragma unroll
    for (int q = 0; q < EPT; ++q)
        if (dA[q] >= 0) atomicAdd(&hist[dA[q] >> 9], 1);
    __syncthreads();
    if (t == 0) {
        int s = 0;
        for (int b = 0; b < NB; ++b) { excl[b] = s; s += hist[b]; }
        excl[NB] = s;
    }
    __syncthreads();
    if (t < NB) {
        gpos[t] = atomicAdd(&bcnt[t], hist[t]);
        cur[t] = excl[t];
    }
    __syncthreads();
    #pragma unroll
    for (int q = 0; q < EPT; ++q) {
        if (dA[q] >= 0) {
            int b = dA[q] >> 9;
            int lp = atomicAdd(&cur[b], 1);
            sorted[lp] = ((uint32)(dA[q] & (BINW - 1)) << 16) | (uint32)sA[q];
        }
    }
    __syncthreads();
    for (int i = t; i < n; i += 256) {
        int lo = 0, hi = NB - 1;
        while (lo < hi) { int mid = (lo + hi + 1) >> 1; if (excl[mid] <= i) lo = mid; else hi = mid - 1; }
        int gp = gpos[lo] + (i - excl[lo]);
        if (gp < CAP) gbuf[(size_t)lo * CAP + gp] = sorted[i];
    }
}

// tiny scan of bucket counts -> bucket bases; offs[NN] = NE
__global__ void k_bbase(const int* __restrict__ bcnt, int* __restrict__ bbase,
                        int* __restrict__ offs) {
    if (threadIdx.x == 0) {
        int s = 0;
        for (int b = 0; b < NB; ++b) { bbase[b] = s; s += bcnt[b]; }
        offs[NN] = s;
    }
}

// ---------------------------------------------------------------------------
// k_sort: one block per bucket -> offs[] + dst-sorted src list (uint16)
// ---------------------------------------------------------------------------
__global__ __launch_bounds__(256) void k_sort(const uint32* __restrict__ gbuf,
                                              const int* __restrict__ bcnt,
                                              const int* __restrict__ bbase,
                                              int* __restrict__ offs,
                                              unsigned short* __restrict__ ssrc) {
    __shared__ int hist[BINW], cur[BINW], wsum[4];
    __shared__ int sorted[CAP];
    int b = blockIdx.x, t = threadIdx.x;
    int cnt = bcnt[b]; if (cnt > CAP) cnt = CAP;
    int nbase = b * BINW;
    int ncnt = NN - nbase; if (ncnt > BINW) ncnt = BINW;
    for (int i = t; i < BINW; i += 256) hist[i] = 0;
    __syncthreads();
    for (int i = t; i < cnt; i += 256)
        atomicAdd(&hist[gbuf[(size_t)b * CAP + i] >> 16], 1);
    __syncthreads();
    int lane = t & 63, w = t >> 6;
    int d0 = hist[2 * t], d1 = hist[2 * t + 1];
    int v = d0 + d1;
    #pragma unroll
    for (int d = 1; d < 64; d <<= 1) { int x = __shfl_up(v, d); if (lane >= d) v += x; }
    if (lane == 63) wsum[w] = v;
    __syncthreads();
    if (t == 0) { int s = 0; for (int i = 0; i < 4; ++i) { int x = wsum[i]; wsum[i] = s; s += x; } }
    __syncthreads();
    int e0 = wsum[w] + (v - d0 - d1);
    int e1 = e0 + d0;
    if (2 * t < ncnt)     offs[nbase + 2 * t]     = bbase[b] + e0;
    if (2 * t + 1 < ncnt) offs[nbase + 2 * t + 1] = bbase[b] + e1;
    cur[2 * t] = e0; cur[2 * t + 1] = e1;
    __syncthreads();
    for (int i = t; i < cnt; i += 256) {
        uint32 p = gbuf[(size_t)b * CAP + i];
        int lp = atomicAdd(&cur[p >> 16], 1);
        sorted[lp] = (int)(p & 0xFFFFu);
    }
    __syncthreads();
    for (int i = t; i < cnt; i += 256)
        ssrc[bbase[b] + i] = (unsigned short)sorted[i];
}

// ---------------------------------------------------------------------------
// quad burst-gather: wave = 4 groups of 16 lanes; each group loads one full
// 256B row per uint4 instruction -> 4 rows per wave-instruction, 16 rows in
// flight per burst. Groups are channel-redundant; reduce via shfl_xor(16,32).
// ---------------------------------------------------------------------------
#define ACC8(vv) { a[0] += bf_lo((vv).x); a[1] += bf_hi((vv).x); \
                   a[2] += bf_lo((vv).y); a[3] += bf_hi((vv).y); \
                   a[4] += bf_lo((vv).z); a[5] += bf_hi((vv).z); \
                   a[6] += bf_lo((vv).w); a[7] += bf_hi((vv).w); }

__device__ inline void burst_gather4(const unsigned short* __restrict__ tab, int coff,
                                     const unsigned short* __restrict__ ssrc, int s0, int s1,
                                     int lane, float* a) {
    int grp = lane >> 4, cl = lane & 15;
    const unsigned short* bp = tab + coff + cl * 8;
    int e = s0;
    while (e < s1) {
        int cnt = s1 - e; if (cnt > 64) cnt = 64;
        int myidx = (lane < cnt) ? (int)ssrc[e + lane] : 0;
        for (int r0 = 0; r0 < cnt; r0 += 16) {
            uint4 v[4]; bool ok[4];
            #pragma unroll
            for (int u = 0; u < 4; ++u) {
                int r = r0 + u * 4 + grp;
                ok[u] = r < cnt;
                int s = __shfl(myidx, r & 63);   // lanes >= cnt hold 0 -> safe row
                v[u] = *(const uint4*)(bp + (size_t)s * 256);
            }
            #pragma unroll
            for (int u = 0; u < 4; ++u) if (ok[u]) ACC8(v[u]);
        }
        e += cnt;
    }
}

__device__ inline void xreduce8(float* a) {
    #pragma unroll
    for (int k = 0; k < 8; ++k) {
        a[k] += __shfl_xor(a[k], 16);
        a[k] += __shfl_xor(a[k], 32);
    }
}

// ---------------------------------------------------------------------------
// mean-aggregate bf16 rows (A1 cols 128:256) -> bf16 (A1 cols 0:128)
// ---------------------------------------------------------------------------
__global__ void k_agg(unsigned short* __restrict__ A1, const int* __restrict__ offs,
                      const unsigned short* __restrict__ ssrc) {
    int node = blockIdx.x * 4 + (threadIdx.x >> 6);
    int lane = threadIdx.x & 63;
    if (node >= NN) return;
    int cl = lane & 15;
    int s0 = offs[node], s1 = offs[node + 1];
    float a[8] = {};
    burst_gather4(A1, 128, ssrc, s0, s1, lane, a);
    xreduce8(a);
    float inv = 1.0f / fmaxf((float)(s1 - s0), 1.0f);
    if (lane < 16) {
        uint4 p;
        p.x = f2bf(a[0] * inv) | ((uint32)f2bf(a[1] * inv) << 16);
        p.y = f2bf(a[2] * inv) | ((uint32)f2bf(a[3] * inv) << 16);
        p.z = f2bf(a[4] * inv) | ((uint32)f2bf(a[5] * inv) << 16);
        p.w = f2bf(a[6] * inv) | ((uint32)f2bf(a[7] * inv) << 16);
        *(uint4*)(A1 + (size_t)node * 256 + cl * 8) = p;
    }
}

// ---------------------------------------------------------------------------
// bf16 MFMA GEMM: [NN,256] @ [256,256] -> [NN,256] bf16
// 128x128 tile, 4 waves (2x2), 4x4 frags of 16x16x32, BK=32.
// 2-phase pipeline: dbuf LDS, register-prefetch of K-step k+1 issued before
// the ds_read+MFMA of step k; one barrier per K-step.
// ---------------------------------------------------------------------------
template <bool RELU>
__global__ __launch_bounds__(256)
void k_gemm_bf(const unsigned short* __restrict__ A, const unsigned short* __restrict__ Bt,
               const float* __restrict__ bias, unsigned short* __restrict__ C) {
    constexpr int LDK = 40;  // 32 + 8 bf16 pad
    __shared__ unsigned short Asm[2][128][LDK];
    __shared__ unsigned short Bsm[2][128][LDK];
    int t = threadIdx.x;
    int lane = t & 63, w = t >> 6;
    int m0 = blockIdx.x * 128, n0 = blockIdx.y * 128;
    int wr = (w >> 1) * 64, wc = (w & 1) * 64;
    int fr = lane & 15, fk = (lane >> 4) * 8;

    f32x4 acc[4][4] = {};
    int ml = t >> 2, sub = t & 3;
    int gmA0 = m0 + ml, gmA1 = m0 + ml + 64;
    bool okA0 = gmA0 < NN, okA1 = gmA1 < NN;
    const short8* pa0 = (const short8*)(A + (size_t)gmA0 * 256 + sub * 8);
    const short8* pa1 = (const short8*)(A + (size_t)gmA1 * 256 + sub * 8);
    const short8* pb0 = (const short8*)(Bt + (size_t)(n0 + ml) * 256 + sub * 8);
    const short8* pb1 = (const short8*)(Bt + (size_t)(n0 + ml + 64) * 256 + sub * 8);
    const short8 zero = {};

    short8 va0, va1, vb0, vb1;
    auto LOAD = [&](int ks) {
        va0 = okA0 ? pa0[ks * 4] : zero;
        va1 = okA1 ? pa1[ks * 4] : zero;
        vb0 = pb0[ks * 4];
        vb1 = pb1[ks * 4];
    };
    auto STORE = [&](int buf) {
        *(short8*)&Asm[buf][ml][sub * 8]      = va0;
        *(short8*)&Asm[buf][ml + 64][sub * 8] = va1;
        *(short8*)&Bsm[buf][ml][sub * 8]      = vb0;
        *(short8*)&Bsm[buf][ml + 64][sub * 8] = vb1;
    };

    LOAD(0);
    STORE(0);
    __syncthreads();
    int cur = 0;
    #pragma unroll
    for (int ks = 0; ks < 8; ++ks) {
        if (ks < 7) LOAD(ks + 1);
        short8 af[4], bfr[4];
        #pragma unroll
        for (int i = 0; i < 4; ++i) af[i] = *(const short8*)&Asm[cur][wr + i * 16 + fr][fk];
        #pragma unroll
        for (int j = 0; j < 4; ++j) bfr[j] = *(const short8*)&Bsm[cur][wc + j * 16 + fr][fk];
        #pragma unroll
        for (int i = 0; i < 4; ++i)
            #pragma unroll
            for (int j = 0; j < 4; ++j)
                acc[i][j] = __builtin_amdgcn_mfma_f32_16x16x32_bf16(af[i], bfr[j], acc[i][j], 0, 0, 0);
        if (ks < 7) {
            STORE(cur ^ 1);
            __syncthreads();
            cur ^= 1;
        }
    }

    int r0 = (lane >> 4) * 4;
    #pragma unroll
    for (int i = 0; i < 4; ++i) {
        #pragma unroll
        for (int j = 0; j < 4; ++j) {
            int gn = n0 + wc + j * 16 + fr;
            float bb = RELU ? bias[gn] : 0.f;
            #pragma unroll
            for (int rr = 0; rr < 4; ++rr) {
                int gm = m0 + wr + i * 16 + r0 + rr;
                if (gm >= NN) continue;
                float v = acc[i][j][rr];
                if (RELU) v = fmaxf(v + bb, 0.f);
                C[(size_t)gm * 256 + gn] = f2bf(v);
            }
        }
    }
}

// ---------------------------------------------------------------------------
// out = log_softmax( mean_agg(p) + r + b2 ); p = P cols 0:128, r = cols 128:256
// ---------------------------------------------------------------------------
__global__ void k_final(const unsigned short* __restrict__ P, const int* __restrict__ offs,
                        const unsigned short* __restrict__ ssrc, const float* __restrict__ b2,
                        float* __restrict__ out) {
    int node = blockIdx.x * 4 + (threadIdx.x >> 6);
    int lane = threadIdx.x & 63;
    if (node >= NN) return;
    int cl = lane & 15;
    int s0 = offs[node], s1 = offs[node + 1];
    float a[8] = {};
    burst_gather4(P, 0, ssrc, s0, s1, lane, a);
    xreduce8(a);
    float inv = 1.0f / fmaxf((float)(s1 - s0), 1.0f);
    uint4 rv = *(const uint4*)(P + (size_t)node * 256 + 128 + cl * 8);
    float4 ba = *(const float4*)(b2 + cl * 8);
    float4 bb = *(const float4*)(b2 + cl * 8 + 4);
    float vv[8];
    vv[0] = a[0] * inv + bf_lo(rv.x) + ba.x;
    vv[1] = a[1] * inv + bf_hi(rv.x) + ba.y;
    vv[2] = a[2] * inv + bf_lo(rv.y) + ba.z;
    vv[3] = a[3] * inv + bf_hi(rv.y) + ba.w;
    vv[4] = a[4] * inv + bf_lo(rv.z) + bb.x;
    vv[5] = a[5] * inv + bf_hi(rv.z) + bb.y;
    vv[6] = a[6] * inv + bf_lo(rv.w) + bb.z;
    vv[7] = a[7] * inv + bf_hi(rv.w) + bb.w;

    float mx = vv[0];
    #pragma unroll
    for (int k = 1; k < 8; ++k) mx = fmaxf(mx, vv[k]);
    #pragma unroll
    for (int d = 1; d < 16; d <<= 1) mx = fmaxf(mx, __shfl_xor(mx, d));
    float s = 0.f;
    #pragma unroll
    for (int k = 0; k < 8; ++k) s += __expf(vv[k] - mx);
    #pragma unroll
    for (int d = 1; d < 16; d <<= 1) s += __shfl_xor(s, d);
    float ls = logf(s);
    if (lane < 16) {
        float4 o0 = make_float4(vv[0] - mx - ls, vv[1] - mx - ls, vv[2] - mx - ls, vv[3] - mx - ls);
        float4 o1 = make_float4(vv[4] - mx - ls, vv[5] - mx - ls, vv[6] - mx - ls, vv[7] - mx - ls);
        *(float4*)(out + (size_t)node * 128 + cl * 8) = o0;
        *(float4*)(out + (size_t)node * 128 + cl * 8 + 4) = o1;
    }
}

// ---------------------------------------------------------------------------
extern "C" void kernel_launch(void* const* d_in, const int* in_sizes, int n_in,
                              void* d_out, int out_size, void* d_ws, size_t ws_size,
                              hipStream_t stream) {
    const float* x   = (const float*)d_in[0];
    const void*  edg = d_in[1];
    const float* W1l = (const float*)d_in[2];
    const float* W1r = (const float*)d_in[3];
    const float* b1  = (const float*)d_in[4];
    const float* W2l = (const float*)d_in[5];
    const float* W2r = (const float*)d_in[6];
    const float* b2  = (const float*)d_in[7];
    float* out = (float*)d_out;

    char* ws = (char*)d_ws;
    size_t off = 0;
    auto alloc = [&](size_t bytes) {
        size_t cur = off;
        off = (off + bytes + 255) & ~(size_t)255;
        return cur;
    };
    int* flag  = (int*)(ws + alloc(4));
    int* bcnt  = (int*)(ws + alloc((size_t)NB * 4));
    int* bbase = (int*)(ws + alloc((size_t)NB * 4));
    int* offs  = (int*)(ws + alloc((size_t)(NN + 1) * 4));
    unsigned short* ssrc = (unsigned short*)(ws + alloc((size_t)NE * 2));
    uint32* gbuf = (uint32*)(ws + alloc((size_t)NB * CAP * 4));              // 4.8MB
    unsigned short* A1  = (unsigned short*)(ws + alloc((size_t)NN * 256 * 2)); // [agg|x] bf16
    unsigned short* Hb  = (unsigned short*)(ws + alloc((size_t)NN * 256 * 2)); // h bf16
    unsigned short* Pb  = (unsigned short*)(ws + alloc((size_t)NN * 256 * 2)); // [p|r] bf16
    unsigned short* B1t = (unsigned short*)(ws + alloc((size_t)65536 * 2));
    unsigned short* B2t = (unsigned short*)(ws + alloc((size_t)65536 * 2));

    int nb_w = (NN + 3) / 4;
    int mblocks = (NN + 127) / 128;            // 391
    int binblocks = (NE + CHUNK - 1) / CHUNK;  // 196

    k_prep<<<6507, 256, 0, stream>>>(x, A1, W1l, W1r, W2l, W2r, B1t, B2t, flag, bcnt, edg);
    k_bin<<<binblocks, 256, 0, stream>>>(edg, flag, gbuf, bcnt);
    k_bbase<<<1, 64, 0, stream>>>(bcnt, bbase, offs);
    k_sort<<<NB, 256, 0, stream>>>(gbuf, bcnt, bbase, offs, ssrc);
    // agg1 -> A1 cols 0:128
    k_agg<<<nb_w, 256, 0, stream>>>(A1, offs, ssrc);
    // h = relu(A1 @ B1 + b1) -> Hb
    k_gemm_bf<true><<<dim3(mblocks, 2), 256, 0, stream>>>(A1, B1t, b1, Hb);
    // [p|r] = Hb @ B2 -> Pb
    k_gemm_bf<false><<<dim3(mblocks, 2), 256, 0, stream>>>(Hb, B2t, nullptr, Pb);
    // out = log_softmax(mean_agg(p) + r + b2)
    k_final<<<nb_w, 256, 0, stream>>>(Pb, offs, ssrc, b2, out);
}